// Round 6
// baseline (413.241 us; speedup 1.0000x reference)
//
#include <hip/hip_runtime.h>
#include <math.h>

// ---------------- packed-fp32 helpers (v_pk_* on gfx90a+/gfx950) ----------------
// Two batch elements per thread ride in the two halves of an f32x2. Weights are
// wave-uniform scalars broadcast via bc2 (op_sel makes this free). Each packed
// fma component executes the exact scalar fma chain of v6 -> bit-identical.
typedef float f32x2 __attribute__((ext_vector_type(2)));

__device__ __forceinline__ f32x2 bc2(float s) { return (f32x2){s, s}; }
__device__ __forceinline__ f32x2 fma2(f32x2 a, f32x2 b, f32x2 c) {
    return __builtin_elementwise_fma(a, b, c);
}
__device__ __forceinline__ f32x2 max02(f32x2 v) {
    return __builtin_elementwise_max(v, (f32x2){0.f, 0.f});
}

// tanh(x) = 1 - 2/(e^{2x}+1); e^{2x} = exp2(x * 2*log2(e))
__device__ __forceinline__ float fast_tanh(float x) {
    float t = __builtin_amdgcn_exp2f(x * 2.8853900817779268f);
    return fmaf(-2.0f, __builtin_amdgcn_rcpf(t + 1.0f), 1.0f);
}
__device__ __forceinline__ f32x2 tanh2(f32x2 z) {
    f32x2 r; r.x = fast_tanh(z.x); r.y = fast_tanh(z.y); return r;
}

// ---------------- ODE helpers: RK4 with 3x3 Jacobian, re-linearized every 3 steps ----
// All state packed (elemA, elemB) per register pair.
struct OdeState {
    f32x2 y0, y1, y2;
    f32x2 yb0, yb1, yb2;
    f32x2 kb0, kb1, kb2;
    f32x2 J00, J01, J02, J10, J11, J12, J20, J21, J22;
};

__device__ __forceinline__ void relin_begin(OdeState& S, float c0, float c1, float c2) {
    S.yb0 = S.y0; S.yb1 = S.y1; S.yb2 = S.y2;
    S.kb0 = bc2(c0); S.kb1 = bc2(c1); S.kb2 = bc2(c2);
    S.J00 = bc2(0.f); S.J01 = bc2(0.f); S.J02 = bc2(0.f);
    S.J10 = bc2(0.f); S.J11 = bc2(0.f); S.J12 = bc2(0.f);
    S.J20 = bc2(0.f); S.J21 = bc2(0.f); S.J22 = bc2(0.f);
}

__device__ __forceinline__ void accum_quad(OdeState& S,
        const float4& z, const float4& wa, const float4& wb, const float4& wc,
        const float4& u0, const float4& u1, const float4& u2)
{
    // z_j = fmaf(y0, wa_j, fmaf(y1, wb_j, fmaf(y2, wc_j, z_j)))  (same nesting as v6)
    f32x2 zx = fma2(S.y0, bc2(wa.x), fma2(S.y1, bc2(wb.x), fma2(S.y2, bc2(wc.x), bc2(z.x))));
    f32x2 zy = fma2(S.y0, bc2(wa.y), fma2(S.y1, bc2(wb.y), fma2(S.y2, bc2(wc.y), bc2(z.y))));
    f32x2 zz = fma2(S.y0, bc2(wa.z), fma2(S.y1, bc2(wb.z), fma2(S.y2, bc2(wc.z), bc2(z.z))));
    f32x2 zw = fma2(S.y0, bc2(wa.w), fma2(S.y1, bc2(wb.w), fma2(S.y2, bc2(wc.w), bc2(z.w))));
    f32x2 t0 = tanh2(zx);
    f32x2 t1 = tanh2(zy);
    f32x2 t2 = tanh2(zz);
    f32x2 t3 = tanh2(zw);
    f32x2 g0 = fma2(-t0, t0, bc2(1.0f));
    f32x2 g1 = fma2(-t1, t1, bc2(1.0f));
    f32x2 g2 = fma2(-t2, t2, bc2(1.0f));
    f32x2 g3 = fma2(-t3, t3, bc2(1.0f));
    S.kb0 = fma2(t0, bc2(u0.x), S.kb0); S.kb1 = fma2(t0, bc2(u0.y), S.kb1); S.kb2 = fma2(t0, bc2(u0.z), S.kb2);
    S.kb0 = fma2(t1, bc2(u0.w), S.kb0); S.kb1 = fma2(t1, bc2(u1.x), S.kb1); S.kb2 = fma2(t1, bc2(u1.y), S.kb2);
    S.kb0 = fma2(t2, bc2(u1.z), S.kb0); S.kb1 = fma2(t2, bc2(u1.w), S.kb1); S.kb2 = fma2(t2, bc2(u2.x), S.kb2);
    S.kb0 = fma2(t3, bc2(u2.y), S.kb0); S.kb1 = fma2(t3, bc2(u2.z), S.kb1); S.kb2 = fma2(t3, bc2(u2.w), S.kb2);
    {
        f32x2 q0 = g0 * bc2(u0.x), q1 = g0 * bc2(u0.y), q2 = g0 * bc2(u0.z);
        S.J00 = fma2(bc2(wa.x), q0, S.J00); S.J01 = fma2(bc2(wa.x), q1, S.J01); S.J02 = fma2(bc2(wa.x), q2, S.J02);
        S.J10 = fma2(bc2(wb.x), q0, S.J10); S.J11 = fma2(bc2(wb.x), q1, S.J11); S.J12 = fma2(bc2(wb.x), q2, S.J12);
        S.J20 = fma2(bc2(wc.x), q0, S.J20); S.J21 = fma2(bc2(wc.x), q1, S.J21); S.J22 = fma2(bc2(wc.x), q2, S.J22);
    }
    {
        f32x2 q0 = g1 * bc2(u0.w), q1 = g1 * bc2(u1.x), q2 = g1 * bc2(u1.y);
        S.J00 = fma2(bc2(wa.y), q0, S.J00); S.J01 = fma2(bc2(wa.y), q1, S.J01); S.J02 = fma2(bc2(wa.y), q2, S.J02);
        S.J10 = fma2(bc2(wb.y), q0, S.J10); S.J11 = fma2(bc2(wb.y), q1, S.J11); S.J12 = fma2(bc2(wb.y), q2, S.J12);
        S.J20 = fma2(bc2(wc.y), q0, S.J20); S.J21 = fma2(bc2(wc.y), q1, S.J21); S.J22 = fma2(bc2(wc.y), q2, S.J22);
    }
    {
        f32x2 q0 = g2 * bc2(u1.z), q1 = g2 * bc2(u1.w), q2 = g2 * bc2(u2.x);
        S.J00 = fma2(bc2(wa.z), q0, S.J00); S.J01 = fma2(bc2(wa.z), q1, S.J01); S.J02 = fma2(bc2(wa.z), q2, S.J02);
        S.J10 = fma2(bc2(wb.z), q0, S.J10); S.J11 = fma2(bc2(wb.z), q1, S.J11); S.J12 = fma2(bc2(wb.z), q2, S.J12);
        S.J20 = fma2(bc2(wc.z), q0, S.J20); S.J21 = fma2(bc2(wc.z), q1, S.J21); S.J22 = fma2(bc2(wc.z), q2, S.J22);
    }
    {
        f32x2 q0 = g3 * bc2(u2.y), q1 = g3 * bc2(u2.z), q2 = g3 * bc2(u2.w);
        S.J00 = fma2(bc2(wa.w), q0, S.J00); S.J01 = fma2(bc2(wa.w), q1, S.J01); S.J02 = fma2(bc2(wa.w), q2, S.J02);
        S.J10 = fma2(bc2(wb.w), q0, S.J10); S.J11 = fma2(bc2(wb.w), q1, S.J11); S.J12 = fma2(bc2(wb.w), q2, S.J12);
        S.J20 = fma2(bc2(wc.w), q0, S.J20); S.J21 = fma2(bc2(wc.w), q1, S.J21); S.J22 = fma2(bc2(wc.w), q2, S.J22);
    }
}

__device__ __forceinline__ void rk4_step(OdeState& S, float dt, float hdt)
{
    f32x2 d0 = S.y0 - S.yb0, d1 = S.y1 - S.yb1, d2 = S.y2 - S.yb2;
    f32x2 k10 = S.kb0 + fma2(d0, S.J00, fma2(d1, S.J10, d2 * S.J20));
    f32x2 k11 = S.kb1 + fma2(d0, S.J01, fma2(d1, S.J11, d2 * S.J21));
    f32x2 k12 = S.kb2 + fma2(d0, S.J02, fma2(d1, S.J12, d2 * S.J22));

    f32x2 k20 = fma2(bc2(hdt), fma2(k10, S.J00, fma2(k11, S.J10, k12 * S.J20)), k10);
    f32x2 k21 = fma2(bc2(hdt), fma2(k10, S.J01, fma2(k11, S.J11, k12 * S.J21)), k11);
    f32x2 k22 = fma2(bc2(hdt), fma2(k10, S.J02, fma2(k11, S.J12, k12 * S.J22)), k12);

    f32x2 k30 = fma2(bc2(hdt), fma2(k20, S.J00, fma2(k21, S.J10, k22 * S.J20)), k10);
    f32x2 k31 = fma2(bc2(hdt), fma2(k20, S.J01, fma2(k21, S.J11, k22 * S.J21)), k11);
    f32x2 k32 = fma2(bc2(hdt), fma2(k20, S.J02, fma2(k21, S.J12, k22 * S.J22)), k12);

    f32x2 k40 = fma2(bc2(dt), fma2(k30, S.J00, fma2(k31, S.J10, k32 * S.J20)), k10);
    f32x2 k41 = fma2(bc2(dt), fma2(k30, S.J01, fma2(k31, S.J11, k32 * S.J21)), k11);
    f32x2 k42 = fma2(bc2(dt), fma2(k30, S.J02, fma2(k31, S.J12, k32 * S.J22)), k12);

    float w6 = dt * (1.0f / 6.0f);
    S.y0 += bc2(w6) * (k10 + bc2(2.0f) * (k20 + k30) + k40);
    S.y1 += bc2(w6) * (k11 + bc2(2.0f) * (k21 + k31) + k41);
    S.y2 += bc2(w6) * (k12 + bc2(2.0f) * (k22 + k32) + k42);
}

// ---------------- Fused kernel: projection MLP + RK4 trajectory ----------------
// v8 = v6 + packed fp32 (v_pk_fma_f32). R4 isolated the bottleneck: VALU-issue
// bound (VALUBusy 80.6%, LDS staging time-neutral). The two batch elements per
// thread pair perfectly into VOP3P packed ops (elem-private values in the two
// halves, shared weights broadcast via op_sel) -> ~halves VALU instruction
// count in proj inner + ODE relin. Per-component arithmetic identical to v6.
// (R5 run was an infra failure — container acquisition; resubmitted unchanged.)
__global__ __launch_bounds__(256, 4)
void fused_kernel(const float* __restrict__ sa,
                  const float* __restrict__ pW1, const float* __restrict__ pb1,
                  const float* __restrict__ pW2, const float* __restrict__ pb2,
                  const float* __restrict__ pW3, const float* __restrict__ pb3,
                  const float* __restrict__ T,
                  const float* __restrict__ oW1, const float* __restrict__ ob1,
                  const float* __restrict__ oW2, const float* __restrict__ ob2,
                  float* __restrict__ out, int B)
{
    __shared__ float sW2[10000];            // 100x100 fp32 = 40000B

    // cooperative stage: 2500 float4s across 256 threads (ALL threads, pre-guard)
    {
        const float4* src = (const float4*)pW2;
        float4* dst = (float4*)sW2;
#pragma unroll 1
        for (int idx = threadIdx.x; idx < 2500; idx += 256)
            dst[idx] = src[idx];
    }
    __syncthreads();

    const int half = B >> 1;
    const int i = blockIdx.x * 256 + threadIdx.x;
    if (i >= half) return;
    const int bA = i, bB = i + half;

    // ---------------- phase 1: projection 6 -> 100 (relu) -> 100 (relu) -> 3 ----
    f32x2 x2[6];                            // (xA[k], xB[k])
    {
        const float2* sA = (const float2*)sa + (size_t)bA * 3;
        const float2* sB = (const float2*)sa + (size_t)bB * 3;
        float2 a0 = sA[0], a1 = sA[1], a2 = sA[2];
        float2 b0 = sB[0], b1 = sB[1], b2 = sB[2];
        x2[0] = (f32x2){a0.x, b0.x}; x2[1] = (f32x2){a0.y, b0.y};
        x2[2] = (f32x2){a1.x, b1.x}; x2[3] = (f32x2){a1.y, b1.y};
        x2[4] = (f32x2){a2.x, b2.x}; x2[5] = (f32x2){a2.y, b2.y};
    }

    f32x2 y0p = bc2(pb3[0]), y1p = bc2(pb3[1]), y2p = bc2(pb3[2]);

#pragma unroll 1
    for (int c = 0; c < 5; ++c) {           // 5 chunks of 20 h2-outputs
        const int cb = c * 20;
        f32x2 acc[20];
#pragma unroll
        for (int q = 0; q < 5; ++q) {
            float4 bz = *(const float4*)(pb2 + cb + q * 4);   // 80B-aligned
            acc[q*4+0] = bc2(bz.x); acc[q*4+1] = bc2(bz.y);
            acc[q*4+2] = bc2(bz.z); acc[q*4+3] = bc2(bz.w);
        }
#pragma unroll 1
        for (int i0 = 0; i0 < 100; i0 += 4) {   // rolled: 25 iterations
            // recompute h1[i0..i0+3] packed (24 pk-fma, shared loads)
            float4 hb = *(const float4*)(pb1 + i0);
            f32x2 h0 = bc2(hb.x), h1 = bc2(hb.y), h2 = bc2(hb.z), h3 = bc2(hb.w);
#pragma unroll
            for (int k = 0; k < 6; ++k) {
                float4 w = *(const float4*)(pW1 + k * 100 + i0);
                h0 = fma2(x2[k], bc2(w.x), h0);
                h1 = fma2(x2[k], bc2(w.y), h1);
                h2 = fma2(x2[k], bc2(w.z), h2);
                h3 = fma2(x2[k], bc2(w.w), h3);
            }
            f32x2 hh[4] = {max02(h0), max02(h1), max02(h2), max02(h3)};
            // accumulate 4 rows x 20 cols of pW2 (80 pk-fma, LDS broadcast reads)
#pragma unroll
            for (int r = 0; r < 4; ++r) {
                const float* wrow = sW2 + (i0 + r) * 100 + cb;  // 80B-aligned
                f32x2 h = hh[r];
#pragma unroll
                for (int q = 0; q < 5; ++q) {
                    float4 w = *(const float4*)(wrow + q * 4);
                    acc[q*4+0] = fma2(h, bc2(w.x), acc[q*4+0]);
                    acc[q*4+1] = fma2(h, bc2(w.y), acc[q*4+1]);
                    acc[q*4+2] = fma2(h, bc2(w.z), acc[q*4+2]);
                    acc[q*4+3] = fma2(h, bc2(w.w), acc[q*4+3]);
                }
            }
        }
        // epilogue for this chunk: relu + layer-3 (shared pW3 loads)
#pragma unroll
        for (int j = 0; j < 20; ++j) {
            f32x2 hp = max02(acc[j]);
            const float* u = pW3 + (size_t)(cb + j) * 3;
            y0p = fma2(hp, bc2(u[0]), y0p);
            y1p = fma2(hp, bc2(u[1]), y1p);
            y2p = fma2(hp, bc2(u[2]), y2p);
        }
    }
    // trajectory slot 0 = y0
    {
        float* oA = out + (size_t)bA * 3;
        oA[0] = y0p.x; oA[1] = y1p.x; oA[2] = y2p.x;
        float* oB = out + (size_t)bB * 3;
        oB[0] = y0p.y; oB[1] = y1p.y; oB[2] = y2p.y;
    }

    // ---------------- phase 2: ODE RK4, y0 stays in registers ----------------
    OdeState S;
    S.y0 = y0p; S.y1 = y1p; S.y2 = y2p;
    const float c0 = ob2[0], c1 = ob2[1], c2 = ob2[2];

    relin_begin(S, c0, c1, c2);   // zero-init so state is defined pre-loop

#pragma unroll 1
    for (int s = 0; s < 15; ++s) {
        float dt  = T[s + 1] - T[s];
        float hdt = 0.5f * dt;

        if ((s % 3) == 0) {      // wave-uniform branch: full eval + Jacobian
            relin_begin(S, c0, c1, c2);
#pragma unroll 1
            for (int j0 = 0; j0 < 100; j0 += 4) {   // rolled: weights scalarize
                float4 z  = *(const float4*)(ob1 + j0);
                float4 wa = *(const float4*)(oW1 + 0   + j0);
                float4 wb = *(const float4*)(oW1 + 100 + j0);
                float4 wc = *(const float4*)(oW1 + 200 + j0);
                float4 u0 = *(const float4*)(oW2 + j0 * 3 + 0);
                float4 u1 = *(const float4*)(oW2 + j0 * 3 + 4);
                float4 u2 = *(const float4*)(oW2 + j0 * 3 + 8);
                accum_quad(S, z, wa, wb, wc, u0, u1, u2);
            }
        }

        rk4_step(S, dt, hdt);

        float* oA = out + (size_t)(s + 1) * (size_t)B * 3 + (size_t)bA * 3;
        oA[0] = S.y0.x; oA[1] = S.y1.x; oA[2] = S.y2.x;
        float* oB = out + (size_t)(s + 1) * (size_t)B * 3 + (size_t)bB * 3;
        oB[0] = S.y0.y; oB[1] = S.y1.y; oB[2] = S.y2.y;
    }
}

extern "C" void kernel_launch(void* const* d_in, const int* in_sizes, int n_in,
                              void* d_out, int out_size, void* d_ws, size_t ws_size,
                              hipStream_t stream) {
    const float* sa  = (const float*)d_in[0];
    const float* T   = (const float*)d_in[1];
    const float* pW1 = (const float*)d_in[2];
    const float* pb1 = (const float*)d_in[3];
    const float* pW2 = (const float*)d_in[4];
    const float* pb2 = (const float*)d_in[5];
    const float* pW3 = (const float*)d_in[6];
    const float* pb3 = (const float*)d_in[7];
    const float* oW1 = (const float*)d_in[8];
    const float* ob1 = (const float*)d_in[9];
    const float* oW2 = (const float*)d_in[10];
    const float* ob2 = (const float*)d_in[11];
    float* out = (float*)d_out;

    const int B = in_sizes[0] / 6;            // 524288
    const int grid = (B / 2 + 255) / 256;     // 1024

    fused_kernel<<<grid, 256, 0, stream>>>(sa, pW1, pb1, pW2, pb2, pW3, pb3,
                                           T, oW1, ob1, oW2, ob2, out, B);
}

// Round 7
// 392.825 us; speedup vs baseline: 1.0520x; 1.0520x over previous
//
#include <hip/hip_runtime.h>
#include <math.h>

// ---------------- packed-fp32 helpers ----------------
// Four batch elements per thread as two f32x2 pairs P=(e0,e1), Q=(e2,e3).
// v4/v6/v8 tied at ~353us across wildly different VALU mixes -> bottleneck is
// the per-wave uniform weight-read stream (2500x16B per chunk-pass, ~167us/CU
// at 16 waves). 4 elems/thread halves weight-read instructions per element.
typedef float f32x2 __attribute__((ext_vector_type(2)));

__device__ __forceinline__ f32x2 bc2(float s) { return (f32x2){s, s}; }
__device__ __forceinline__ f32x2 fma2(f32x2 a, f32x2 b, f32x2 c) {
    return __builtin_elementwise_fma(a, b, c);
}
__device__ __forceinline__ f32x2 max02(f32x2 v) {
    return __builtin_elementwise_max(v, (f32x2){0.f, 0.f});
}

// tanh(x) = 1 - 2/(e^{2x}+1); e^{2x} = exp2(x * 2*log2(e))
__device__ __forceinline__ float fast_tanh(float x) {
    float t = __builtin_amdgcn_exp2f(x * 2.8853900817779268f);
    return fmaf(-2.0f, __builtin_amdgcn_rcpf(t + 1.0f), 1.0f);
}
__device__ __forceinline__ f32x2 tanh2(f32x2 z) {
    f32x2 r; r.x = fast_tanh(z.x); r.y = fast_tanh(z.y); return r;
}

// ---------------- ODE helpers: RK4 with 3x3 Jacobian, re-linearized every 3 steps ----
struct OdeState {
    f32x2 y0, y1, y2;
    f32x2 yb0, yb1, yb2;
    f32x2 kb0, kb1, kb2;
    f32x2 J00, J01, J02, J10, J11, J12, J20, J21, J22;
};

__device__ __forceinline__ void relin_begin(OdeState& S, float c0, float c1, float c2) {
    S.yb0 = S.y0; S.yb1 = S.y1; S.yb2 = S.y2;
    S.kb0 = bc2(c0); S.kb1 = bc2(c1); S.kb2 = bc2(c2);
    S.J00 = bc2(0.f); S.J01 = bc2(0.f); S.J02 = bc2(0.f);
    S.J10 = bc2(0.f); S.J11 = bc2(0.f); S.J12 = bc2(0.f);
    S.J20 = bc2(0.f); S.J21 = bc2(0.f); S.J22 = bc2(0.f);
}

__device__ __forceinline__ void accum_quad(OdeState& S,
        const float4& z, const float4& wa, const float4& wb, const float4& wc,
        const float4& u0, const float4& u1, const float4& u2)
{
    f32x2 zx = fma2(S.y0, bc2(wa.x), fma2(S.y1, bc2(wb.x), fma2(S.y2, bc2(wc.x), bc2(z.x))));
    f32x2 zy = fma2(S.y0, bc2(wa.y), fma2(S.y1, bc2(wb.y), fma2(S.y2, bc2(wc.y), bc2(z.y))));
    f32x2 zz = fma2(S.y0, bc2(wa.z), fma2(S.y1, bc2(wb.z), fma2(S.y2, bc2(wc.z), bc2(z.z))));
    f32x2 zw = fma2(S.y0, bc2(wa.w), fma2(S.y1, bc2(wb.w), fma2(S.y2, bc2(wc.w), bc2(z.w))));
    f32x2 t0 = tanh2(zx);
    f32x2 t1 = tanh2(zy);
    f32x2 t2 = tanh2(zz);
    f32x2 t3 = tanh2(zw);
    f32x2 g0 = fma2(-t0, t0, bc2(1.0f));
    f32x2 g1 = fma2(-t1, t1, bc2(1.0f));
    f32x2 g2 = fma2(-t2, t2, bc2(1.0f));
    f32x2 g3 = fma2(-t3, t3, bc2(1.0f));
    S.kb0 = fma2(t0, bc2(u0.x), S.kb0); S.kb1 = fma2(t0, bc2(u0.y), S.kb1); S.kb2 = fma2(t0, bc2(u0.z), S.kb2);
    S.kb0 = fma2(t1, bc2(u0.w), S.kb0); S.kb1 = fma2(t1, bc2(u1.x), S.kb1); S.kb2 = fma2(t1, bc2(u1.y), S.kb2);
    S.kb0 = fma2(t2, bc2(u1.z), S.kb0); S.kb1 = fma2(t2, bc2(u1.w), S.kb1); S.kb2 = fma2(t2, bc2(u2.x), S.kb2);
    S.kb0 = fma2(t3, bc2(u2.y), S.kb0); S.kb1 = fma2(t3, bc2(u2.z), S.kb1); S.kb2 = fma2(t3, bc2(u2.w), S.kb2);
    {
        f32x2 q0 = g0 * bc2(u0.x), q1 = g0 * bc2(u0.y), q2 = g0 * bc2(u0.z);
        S.J00 = fma2(bc2(wa.x), q0, S.J00); S.J01 = fma2(bc2(wa.x), q1, S.J01); S.J02 = fma2(bc2(wa.x), q2, S.J02);
        S.J10 = fma2(bc2(wb.x), q0, S.J10); S.J11 = fma2(bc2(wb.x), q1, S.J11); S.J12 = fma2(bc2(wb.x), q2, S.J12);
        S.J20 = fma2(bc2(wc.x), q0, S.J20); S.J21 = fma2(bc2(wc.x), q1, S.J21); S.J22 = fma2(bc2(wc.x), q2, S.J22);
    }
    {
        f32x2 q0 = g1 * bc2(u0.w), q1 = g1 * bc2(u1.x), q2 = g1 * bc2(u1.y);
        S.J00 = fma2(bc2(wa.y), q0, S.J00); S.J01 = fma2(bc2(wa.y), q1, S.J01); S.J02 = fma2(bc2(wa.y), q2, S.J02);
        S.J10 = fma2(bc2(wb.y), q0, S.J10); S.J11 = fma2(bc2(wb.y), q1, S.J11); S.J12 = fma2(bc2(wb.y), q2, S.J12);
        S.J20 = fma2(bc2(wc.y), q0, S.J20); S.J21 = fma2(bc2(wc.y), q1, S.J21); S.J22 = fma2(bc2(wc.y), q2, S.J22);
    }
    {
        f32x2 q0 = g2 * bc2(u1.z), q1 = g2 * bc2(u1.w), q2 = g2 * bc2(u2.x);
        S.J00 = fma2(bc2(wa.z), q0, S.J00); S.J01 = fma2(bc2(wa.z), q1, S.J01); S.J02 = fma2(bc2(wa.z), q2, S.J02);
        S.J10 = fma2(bc2(wb.z), q0, S.J10); S.J11 = fma2(bc2(wb.z), q1, S.J11); S.J12 = fma2(bc2(wb.z), q2, S.J12);
        S.J20 = fma2(bc2(wc.z), q0, S.J20); S.J21 = fma2(bc2(wc.z), q1, S.J21); S.J22 = fma2(bc2(wc.z), q2, S.J22);
    }
    {
        f32x2 q0 = g3 * bc2(u2.y), q1 = g3 * bc2(u2.z), q2 = g3 * bc2(u2.w);
        S.J00 = fma2(bc2(wa.w), q0, S.J00); S.J01 = fma2(bc2(wa.w), q1, S.J01); S.J02 = fma2(bc2(wa.w), q2, S.J02);
        S.J10 = fma2(bc2(wb.w), q0, S.J10); S.J11 = fma2(bc2(wb.w), q1, S.J11); S.J12 = fma2(bc2(wb.w), q2, S.J12);
        S.J20 = fma2(bc2(wc.w), q0, S.J20); S.J21 = fma2(bc2(wc.w), q1, S.J21); S.J22 = fma2(bc2(wc.w), q2, S.J22);
    }
}

__device__ __forceinline__ void rk4_step(OdeState& S, float dt, float hdt)
{
    f32x2 d0 = S.y0 - S.yb0, d1 = S.y1 - S.yb1, d2 = S.y2 - S.yb2;
    f32x2 k10 = S.kb0 + fma2(d0, S.J00, fma2(d1, S.J10, d2 * S.J20));
    f32x2 k11 = S.kb1 + fma2(d0, S.J01, fma2(d1, S.J11, d2 * S.J21));
    f32x2 k12 = S.kb2 + fma2(d0, S.J02, fma2(d1, S.J12, d2 * S.J22));

    f32x2 k20 = fma2(bc2(hdt), fma2(k10, S.J00, fma2(k11, S.J10, k12 * S.J20)), k10);
    f32x2 k21 = fma2(bc2(hdt), fma2(k10, S.J01, fma2(k11, S.J11, k12 * S.J21)), k11);
    f32x2 k22 = fma2(bc2(hdt), fma2(k10, S.J02, fma2(k11, S.J12, k12 * S.J22)), k12);

    f32x2 k30 = fma2(bc2(hdt), fma2(k20, S.J00, fma2(k21, S.J10, k22 * S.J20)), k10);
    f32x2 k31 = fma2(bc2(hdt), fma2(k20, S.J01, fma2(k21, S.J11, k22 * S.J21)), k11);
    f32x2 k32 = fma2(bc2(hdt), fma2(k20, S.J02, fma2(k21, S.J12, k22 * S.J22)), k12);

    f32x2 k40 = fma2(bc2(dt), fma2(k30, S.J00, fma2(k31, S.J10, k32 * S.J20)), k10);
    f32x2 k41 = fma2(bc2(dt), fma2(k30, S.J01, fma2(k31, S.J11, k32 * S.J21)), k11);
    f32x2 k42 = fma2(bc2(dt), fma2(k30, S.J02, fma2(k31, S.J12, k32 * S.J22)), k12);

    float w6 = dt * (1.0f / 6.0f);
    S.y0 += bc2(w6) * (k10 + bc2(2.0f) * (k20 + k30) + k40);
    S.y1 += bc2(w6) * (k11 + bc2(2.0f) * (k21 + k31) + k41);
    S.y2 += bc2(w6) * (k12 + bc2(2.0f) * (k22 + k32) + k42);
}

// ---------------- Fused kernel: projection MLP + RK4 trajectory ----------------
// v9 = v8 with FOUR elements per thread (pairs P=(b0,b1), Q=(b2,b3)).
// Weight reads (LDS broadcast + scalar streams) are shared by 4 elements ->
// per-element weight-delivery instructions halve. Grid 512, 2 blocks/CU,
// __launch_bounds__(256,2) -> 256-VGPR budget (est ~160, no spill).
// Per-element arithmetic identical to v6/v8 -> absmax exactly 0.0078125.
__global__ __launch_bounds__(256, 2)
void fused_kernel(const float* __restrict__ sa,
                  const float* __restrict__ pW1, const float* __restrict__ pb1,
                  const float* __restrict__ pW2, const float* __restrict__ pb2,
                  const float* __restrict__ pW3, const float* __restrict__ pb3,
                  const float* __restrict__ T,
                  const float* __restrict__ oW1, const float* __restrict__ ob1,
                  const float* __restrict__ oW2, const float* __restrict__ ob2,
                  float* __restrict__ out, int B)
{
    __shared__ float sW2[10000];            // 100x100 fp32 = 40000B

    // cooperative stage: 2500 float4s across 256 threads (ALL threads, pre-guard)
    {
        const float4* src = (const float4*)pW2;
        float4* dst = (float4*)sW2;
#pragma unroll 1
        for (int idx = threadIdx.x; idx < 2500; idx += 256)
            dst[idx] = src[idx];
    }
    __syncthreads();

    const int quarter = B >> 2;
    const int i = blockIdx.x * 256 + threadIdx.x;
    if (i >= quarter) return;
    const int b0 = i, b1 = i + quarter, b2 = i + 2 * quarter, b3 = i + 3 * quarter;

    // ---------------- phase 1: projection 6 -> 100 (relu) -> 100 (relu) -> 3 ----
    f32x2 xP[6], xQ[6];                     // P=(b0,b1), Q=(b2,b3)
    {
        const float2* s0 = (const float2*)sa + (size_t)b0 * 3;
        const float2* s1 = (const float2*)sa + (size_t)b1 * 3;
        float2 a0 = s0[0], a1 = s0[1], a2 = s0[2];
        float2 c0 = s1[0], c1 = s1[1], c2 = s1[2];
        xP[0] = (f32x2){a0.x, c0.x}; xP[1] = (f32x2){a0.y, c0.y};
        xP[2] = (f32x2){a1.x, c1.x}; xP[3] = (f32x2){a1.y, c1.y};
        xP[4] = (f32x2){a2.x, c2.x}; xP[5] = (f32x2){a2.y, c2.y};
    }
    {
        const float2* s0 = (const float2*)sa + (size_t)b2 * 3;
        const float2* s1 = (const float2*)sa + (size_t)b3 * 3;
        float2 a0 = s0[0], a1 = s0[1], a2 = s0[2];
        float2 c0 = s1[0], c1 = s1[1], c2 = s1[2];
        xQ[0] = (f32x2){a0.x, c0.x}; xQ[1] = (f32x2){a0.y, c0.y};
        xQ[2] = (f32x2){a1.x, c1.x}; xQ[3] = (f32x2){a1.y, c1.y};
        xQ[4] = (f32x2){a2.x, c2.x}; xQ[5] = (f32x2){a2.y, c2.y};
    }

    f32x2 y0P = bc2(pb3[0]), y1P = bc2(pb3[1]), y2P = bc2(pb3[2]);
    f32x2 y0Q = y0P, y1Q = y1P, y2Q = y2P;

#pragma unroll 1
    for (int c = 0; c < 5; ++c) {           // 5 chunks of 20 h2-outputs
        const int cb = c * 20;
        f32x2 accP[20], accQ[20];
#pragma unroll
        for (int q = 0; q < 5; ++q) {
            float4 bz = *(const float4*)(pb2 + cb + q * 4);   // 80B-aligned
            accP[q*4+0] = bc2(bz.x); accP[q*4+1] = bc2(bz.y);
            accP[q*4+2] = bc2(bz.z); accP[q*4+3] = bc2(bz.w);
            accQ[q*4+0] = bc2(bz.x); accQ[q*4+1] = bc2(bz.y);
            accQ[q*4+2] = bc2(bz.z); accQ[q*4+3] = bc2(bz.w);
        }
#pragma unroll 1
        for (int i0 = 0; i0 < 100; i0 += 4) {   // rolled: 25 iterations
            // recompute h1[i0..i0+3] for both pairs (48 pk-fma, shared loads)
            float4 hb = *(const float4*)(pb1 + i0);
            f32x2 hP0 = bc2(hb.x), hP1 = bc2(hb.y), hP2 = bc2(hb.z), hP3 = bc2(hb.w);
            f32x2 hQ0 = hP0, hQ1 = hP1, hQ2 = hP2, hQ3 = hP3;
#pragma unroll
            for (int k = 0; k < 6; ++k) {
                float4 w = *(const float4*)(pW1 + k * 100 + i0);
                hP0 = fma2(xP[k], bc2(w.x), hP0);
                hP1 = fma2(xP[k], bc2(w.y), hP1);
                hP2 = fma2(xP[k], bc2(w.z), hP2);
                hP3 = fma2(xP[k], bc2(w.w), hP3);
                hQ0 = fma2(xQ[k], bc2(w.x), hQ0);
                hQ1 = fma2(xQ[k], bc2(w.y), hQ1);
                hQ2 = fma2(xQ[k], bc2(w.z), hQ2);
                hQ3 = fma2(xQ[k], bc2(w.w), hQ3);
            }
            f32x2 hhP[4] = {max02(hP0), max02(hP1), max02(hP2), max02(hP3)};
            f32x2 hhQ[4] = {max02(hQ0), max02(hQ1), max02(hQ2), max02(hQ3)};
            // accumulate 4 rows x 20 cols of pW2 (LDS broadcast, shared by 4 elems)
#pragma unroll
            for (int r = 0; r < 4; ++r) {
                const float* wrow = sW2 + (i0 + r) * 100 + cb;  // 80B-aligned
                f32x2 hP = hhP[r], hQ = hhQ[r];
#pragma unroll
                for (int q = 0; q < 5; ++q) {
                    float4 w = *(const float4*)(wrow + q * 4);
                    accP[q*4+0] = fma2(hP, bc2(w.x), accP[q*4+0]);
                    accP[q*4+1] = fma2(hP, bc2(w.y), accP[q*4+1]);
                    accP[q*4+2] = fma2(hP, bc2(w.z), accP[q*4+2]);
                    accP[q*4+3] = fma2(hP, bc2(w.w), accP[q*4+3]);
                    accQ[q*4+0] = fma2(hQ, bc2(w.x), accQ[q*4+0]);
                    accQ[q*4+1] = fma2(hQ, bc2(w.y), accQ[q*4+1]);
                    accQ[q*4+2] = fma2(hQ, bc2(w.z), accQ[q*4+2]);
                    accQ[q*4+3] = fma2(hQ, bc2(w.w), accQ[q*4+3]);
                }
            }
        }
        // epilogue for this chunk: relu + layer-3 (shared pW3 loads)
#pragma unroll
        for (int j = 0; j < 20; ++j) {
            f32x2 hP = max02(accP[j]);
            f32x2 hQ = max02(accQ[j]);
            const float* u = pW3 + (size_t)(cb + j) * 3;
            float u0 = u[0], u1 = u[1], u2 = u[2];
            y0P = fma2(hP, bc2(u0), y0P); y1P = fma2(hP, bc2(u1), y1P); y2P = fma2(hP, bc2(u2), y2P);
            y0Q = fma2(hQ, bc2(u0), y0Q); y1Q = fma2(hQ, bc2(u1), y1Q); y2Q = fma2(hQ, bc2(u2), y2Q);
        }
    }
    // trajectory slot 0 = y0
    {
        float* o0 = out + (size_t)b0 * 3;
        o0[0] = y0P.x; o0[1] = y1P.x; o0[2] = y2P.x;
        float* o1 = out + (size_t)b1 * 3;
        o1[0] = y0P.y; o1[1] = y1P.y; o1[2] = y2P.y;
        float* o2 = out + (size_t)b2 * 3;
        o2[0] = y0Q.x; o2[1] = y1Q.x; o2[2] = y2Q.x;
        float* o3 = out + (size_t)b3 * 3;
        o3[0] = y0Q.y; o3[1] = y1Q.y; o3[2] = y2Q.y;
    }

    // ---------------- phase 2: ODE RK4, y0 stays in registers ----------------
    OdeState SP, SQ;
    SP.y0 = y0P; SP.y1 = y1P; SP.y2 = y2P;
    SQ.y0 = y0Q; SQ.y1 = y1Q; SQ.y2 = y2Q;
    const float c0 = ob2[0], c1 = ob2[1], c2 = ob2[2];

    relin_begin(SP, c0, c1, c2);   // zero-init so state is defined pre-loop
    relin_begin(SQ, c0, c1, c2);

#pragma unroll 1
    for (int s = 0; s < 15; ++s) {
        float dt  = T[s + 1] - T[s];
        float hdt = 0.5f * dt;

        if ((s % 3) == 0) {      // wave-uniform branch: full eval + Jacobian
            relin_begin(SP, c0, c1, c2);
            relin_begin(SQ, c0, c1, c2);
#pragma unroll 1
            for (int j0 = 0; j0 < 100; j0 += 4) {   // rolled: weights scalarize
                float4 z  = *(const float4*)(ob1 + j0);
                float4 wa = *(const float4*)(oW1 + 0   + j0);
                float4 wb = *(const float4*)(oW1 + 100 + j0);
                float4 wc = *(const float4*)(oW1 + 200 + j0);
                float4 u0 = *(const float4*)(oW2 + j0 * 3 + 0);
                float4 u1 = *(const float4*)(oW2 + j0 * 3 + 4);
                float4 u2 = *(const float4*)(oW2 + j0 * 3 + 8);
                accum_quad(SP, z, wa, wb, wc, u0, u1, u2);
                accum_quad(SQ, z, wa, wb, wc, u0, u1, u2);
            }
        }

        rk4_step(SP, dt, hdt);
        rk4_step(SQ, dt, hdt);

        float* base = out + (size_t)(s + 1) * (size_t)B * 3;
        float* o0 = base + (size_t)b0 * 3;
        o0[0] = SP.y0.x; o0[1] = SP.y1.x; o0[2] = SP.y2.x;
        float* o1 = base + (size_t)b1 * 3;
        o1[0] = SP.y0.y; o1[1] = SP.y1.y; o1[2] = SP.y2.y;
        float* o2 = base + (size_t)b2 * 3;
        o2[0] = SQ.y0.x; o2[1] = SQ.y1.x; o2[2] = SQ.y2.x;
        float* o3 = base + (size_t)b3 * 3;
        o3[0] = SQ.y0.y; o3[1] = SQ.y1.y; o3[2] = SQ.y2.y;
    }
}

extern "C" void kernel_launch(void* const* d_in, const int* in_sizes, int n_in,
                              void* d_out, int out_size, void* d_ws, size_t ws_size,
                              hipStream_t stream) {
    const float* sa  = (const float*)d_in[0];
    const float* T   = (const float*)d_in[1];
    const float* pW1 = (const float*)d_in[2];
    const float* pb1 = (const float*)d_in[3];
    const float* pW2 = (const float*)d_in[4];
    const float* pb2 = (const float*)d_in[5];
    const float* pW3 = (const float*)d_in[6];
    const float* pb3 = (const float*)d_in[7];
    const float* oW1 = (const float*)d_in[8];
    const float* ob1 = (const float*)d_in[9];
    const float* oW2 = (const float*)d_in[10];
    const float* ob2 = (const float*)d_in[11];
    float* out = (float*)d_out;

    const int B = in_sizes[0] / 6;            // 524288
    const int grid = (B / 4 + 255) / 256;     // 512

    fused_kernel<<<grid, 256, 0, stream>>>(sa, pW1, pb1, pW2, pb2, pW3, pb3,
                                           T, oW1, ob1, oW2, ob2, out, B);
}

// Round 8
// 361.650 us; speedup vs baseline: 1.1427x; 1.0862x over previous
//
#include <hip/hip_runtime.h>
#include <math.h>

typedef float f32x2 __attribute__((ext_vector_type(2)));
typedef float f32x4v __attribute__((ext_vector_type(4)));
typedef short short8 __attribute__((ext_vector_type(8)));

__device__ __forceinline__ f32x2 bc2(float s) { return (f32x2){s, s}; }
__device__ __forceinline__ f32x2 fma2(f32x2 a, f32x2 b, f32x2 c) {
    return __builtin_elementwise_fma(a, b, c);
}

// bf16 split helpers (round-to-nearest-even)
__device__ __forceinline__ unsigned short bf16_rne(float f) {
    unsigned int u = __float_as_uint(f);
    u += 0x7FFFu + ((u >> 16) & 1u);
    return (unsigned short)(u >> 16);
}
__device__ __forceinline__ float bf16_to_f(unsigned short h) {
    return __uint_as_float(((unsigned int)h) << 16);
}

// tanh(x) = 1 - 2/(e^{2x}+1)
__device__ __forceinline__ float fast_tanh(float x) {
    float t = __builtin_amdgcn_exp2f(x * 2.8853900817779268f);
    return fmaf(-2.0f, __builtin_amdgcn_rcpf(t + 1.0f), 1.0f);
}
__device__ __forceinline__ f32x2 tanh2(f32x2 z) {
    f32x2 r; r.x = fast_tanh(z.x); r.y = fast_tanh(z.y); return r;
}

// ---------------- ODE helpers (identical to v9) ----------------
struct OdeState {
    f32x2 y0, y1, y2;
    f32x2 yb0, yb1, yb2;
    f32x2 kb0, kb1, kb2;
    f32x2 J00, J01, J02, J10, J11, J12, J20, J21, J22;
};

__device__ __forceinline__ void relin_begin(OdeState& S, float c0, float c1, float c2) {
    S.yb0 = S.y0; S.yb1 = S.y1; S.yb2 = S.y2;
    S.kb0 = bc2(c0); S.kb1 = bc2(c1); S.kb2 = bc2(c2);
    S.J00 = bc2(0.f); S.J01 = bc2(0.f); S.J02 = bc2(0.f);
    S.J10 = bc2(0.f); S.J11 = bc2(0.f); S.J12 = bc2(0.f);
    S.J20 = bc2(0.f); S.J21 = bc2(0.f); S.J22 = bc2(0.f);
}

__device__ __forceinline__ void accum_quad(OdeState& S,
        const float4& z, const float4& wa, const float4& wb, const float4& wc,
        const float4& u0, const float4& u1, const float4& u2)
{
    f32x2 zx = fma2(S.y0, bc2(wa.x), fma2(S.y1, bc2(wb.x), fma2(S.y2, bc2(wc.x), bc2(z.x))));
    f32x2 zy = fma2(S.y0, bc2(wa.y), fma2(S.y1, bc2(wb.y), fma2(S.y2, bc2(wc.y), bc2(z.y))));
    f32x2 zz = fma2(S.y0, bc2(wa.z), fma2(S.y1, bc2(wb.z), fma2(S.y2, bc2(wc.z), bc2(z.z))));
    f32x2 zw = fma2(S.y0, bc2(wa.w), fma2(S.y1, bc2(wb.w), fma2(S.y2, bc2(wc.w), bc2(z.w))));
    f32x2 t0 = tanh2(zx);
    f32x2 t1 = tanh2(zy);
    f32x2 t2 = tanh2(zz);
    f32x2 t3 = tanh2(zw);
    f32x2 g0 = fma2(-t0, t0, bc2(1.0f));
    f32x2 g1 = fma2(-t1, t1, bc2(1.0f));
    f32x2 g2 = fma2(-t2, t2, bc2(1.0f));
    f32x2 g3 = fma2(-t3, t3, bc2(1.0f));
    S.kb0 = fma2(t0, bc2(u0.x), S.kb0); S.kb1 = fma2(t0, bc2(u0.y), S.kb1); S.kb2 = fma2(t0, bc2(u0.z), S.kb2);
    S.kb0 = fma2(t1, bc2(u0.w), S.kb0); S.kb1 = fma2(t1, bc2(u1.x), S.kb1); S.kb2 = fma2(t1, bc2(u1.y), S.kb2);
    S.kb0 = fma2(t2, bc2(u1.z), S.kb0); S.kb1 = fma2(t2, bc2(u1.w), S.kb1); S.kb2 = fma2(t2, bc2(u2.x), S.kb2);
    S.kb0 = fma2(t3, bc2(u2.y), S.kb0); S.kb1 = fma2(t3, bc2(u2.z), S.kb1); S.kb2 = fma2(t3, bc2(u2.w), S.kb2);
    {
        f32x2 q0 = g0 * bc2(u0.x), q1 = g0 * bc2(u0.y), q2 = g0 * bc2(u0.z);
        S.J00 = fma2(bc2(wa.x), q0, S.J00); S.J01 = fma2(bc2(wa.x), q1, S.J01); S.J02 = fma2(bc2(wa.x), q2, S.J02);
        S.J10 = fma2(bc2(wb.x), q0, S.J10); S.J11 = fma2(bc2(wb.x), q1, S.J11); S.J12 = fma2(bc2(wb.x), q2, S.J12);
        S.J20 = fma2(bc2(wc.x), q0, S.J20); S.J21 = fma2(bc2(wc.x), q1, S.J21); S.J22 = fma2(bc2(wc.x), q2, S.J22);
    }
    {
        f32x2 q0 = g1 * bc2(u0.w), q1 = g1 * bc2(u1.x), q2 = g1 * bc2(u1.y);
        S.J00 = fma2(bc2(wa.y), q0, S.J00); S.J01 = fma2(bc2(wa.y), q1, S.J01); S.J02 = fma2(bc2(wa.y), q2, S.J02);
        S.J10 = fma2(bc2(wb.y), q0, S.J10); S.J11 = fma2(bc2(wb.y), q1, S.J11); S.J12 = fma2(bc2(wb.y), q2, S.J12);
        S.J20 = fma2(bc2(wc.y), q0, S.J20); S.J21 = fma2(bc2(wc.y), q1, S.J21); S.J22 = fma2(bc2(wc.y), q2, S.J22);
    }
    {
        f32x2 q0 = g2 * bc2(u1.z), q1 = g2 * bc2(u1.w), q2 = g2 * bc2(u2.x);
        S.J00 = fma2(bc2(wa.z), q0, S.J00); S.J01 = fma2(bc2(wa.z), q1, S.J01); S.J02 = fma2(bc2(wa.z), q2, S.J02);
        S.J10 = fma2(bc2(wb.z), q0, S.J10); S.J11 = fma2(bc2(wb.z), q1, S.J11); S.J12 = fma2(bc2(wb.z), q2, S.J12);
        S.J20 = fma2(bc2(wc.z), q0, S.J20); S.J21 = fma2(bc2(wc.z), q1, S.J21); S.J22 = fma2(bc2(wc.z), q2, S.J22);
    }
    {
        f32x2 q0 = g3 * bc2(u2.y), q1 = g3 * bc2(u2.z), q2 = g3 * bc2(u2.w);
        S.J00 = fma2(bc2(wa.w), q0, S.J00); S.J01 = fma2(bc2(wa.w), q1, S.J01); S.J02 = fma2(bc2(wa.w), q2, S.J02);
        S.J10 = fma2(bc2(wb.w), q0, S.J10); S.J11 = fma2(bc2(wb.w), q1, S.J11); S.J12 = fma2(bc2(wb.w), q2, S.J12);
        S.J20 = fma2(bc2(wc.w), q0, S.J20); S.J21 = fma2(bc2(wc.w), q1, S.J21); S.J22 = fma2(bc2(wc.w), q2, S.J22);
    }
}

__device__ __forceinline__ void rk4_step(OdeState& S, float dt, float hdt)
{
    f32x2 d0 = S.y0 - S.yb0, d1 = S.y1 - S.yb1, d2 = S.y2 - S.yb2;
    f32x2 k10 = S.kb0 + fma2(d0, S.J00, fma2(d1, S.J10, d2 * S.J20));
    f32x2 k11 = S.kb1 + fma2(d0, S.J01, fma2(d1, S.J11, d2 * S.J21));
    f32x2 k12 = S.kb2 + fma2(d0, S.J02, fma2(d1, S.J12, d2 * S.J22));

    f32x2 k20 = fma2(bc2(hdt), fma2(k10, S.J00, fma2(k11, S.J10, k12 * S.J20)), k10);
    f32x2 k21 = fma2(bc2(hdt), fma2(k10, S.J01, fma2(k11, S.J11, k12 * S.J21)), k11);
    f32x2 k22 = fma2(bc2(hdt), fma2(k10, S.J02, fma2(k11, S.J12, k12 * S.J22)), k12);

    f32x2 k30 = fma2(bc2(hdt), fma2(k20, S.J00, fma2(k21, S.J10, k22 * S.J20)), k10);
    f32x2 k31 = fma2(bc2(hdt), fma2(k20, S.J01, fma2(k21, S.J11, k22 * S.J21)), k11);
    f32x2 k32 = fma2(bc2(hdt), fma2(k20, S.J02, fma2(k21, S.J12, k22 * S.J22)), k12);

    f32x2 k40 = fma2(bc2(dt), fma2(k30, S.J00, fma2(k31, S.J10, k32 * S.J20)), k10);
    f32x2 k41 = fma2(bc2(dt), fma2(k30, S.J01, fma2(k31, S.J11, k32 * S.J21)), k11);
    f32x2 k42 = fma2(bc2(dt), fma2(k30, S.J02, fma2(k31, S.J12, k32 * S.J22)), k12);

    float w6 = dt * (1.0f / 6.0f);
    S.y0 += bc2(w6) * (k10 + bc2(2.0f) * (k20 + k30) + k40);
    S.y1 += bc2(w6) * (k11 + bc2(2.0f) * (k21 + k31) + k41);
    S.y2 += bc2(w6) * (k12 + bc2(2.0f) * (k22 + k32) + k42);
}

// ---------------- Fused kernel v10: MFMA split-bf16 proj + v9 ODE ----------------
// v4/v6/v8/v9 tied at 338-355us across different VALU mixes: proj is VALU-issue
// bound and incremental shaves plateaued. h1@W2 is a [B x 100][100 x 100] GEMM
// -> matrix cores. Split-bf16 (hi+lo, 3 MFMA terms, drop lo*lo): rel err ~2^-16,
// y0 perturbation ~1e-4 << 7.8e-3 relin error. Layouts (guide §3, m89-verified
// C/D): A[i][k]: i=lane&15, k=kt*32+(lane>>4)*8+b; B[k][n]: n=lane&15, same k;
// D: row=(lane>>4)*4+reg, col=lane&15. Wave: 16 tiles x 16 rows = 256 rows.
// After col-reduce (shfl_xor 1/2/4/8), lane keeps tile t==lane&15 -> owns rows
// wave_base + (lane&15)*16 + (lane>>4)*4 + {0..3}; ODE (v9, unchanged) on 4
// rows/lane as two f32x2 pairs.
__global__ __launch_bounds__(256, 2)
void fused_kernel(const float* __restrict__ sa,
                  const float* __restrict__ pW1, const float* __restrict__ pb1,
                  const float* __restrict__ pW2, const float* __restrict__ pb2,
                  const float* __restrict__ pW3, const float* __restrict__ pb3,
                  const float* __restrict__ T,
                  const float* __restrict__ oW1, const float* __restrict__ ob1,
                  const float* __restrict__ oW2, const float* __restrict__ ob2,
                  float* __restrict__ out, int B)
{
    // W2 as bf16 hi/lo MFMA B-fragments, K padded to 128, N padded to 112.
    // Frag layout: s[( (kt*7+nt)*64 + lane )*8 + b], 16B per lane per frag.
    __shared__ short sHi[14336];   // 4 kt * 7 nt * 64 lanes * 8 bf16
    __shared__ short sLo[14336];

#pragma unroll 1
    for (int it = 0; it < 56; ++it) {
        int f = it * 256 + threadIdx.x;          // 0..14335
        int lane_s = f & 63;
        int b = (f >> 6) & 7;
        int t2 = f >> 9;                          // (kt*7+nt) 0..27
        int nt = t2 % 7, kt = t2 / 7;
        int k = kt * 32 + (lane_s >> 4) * 8 + b;
        int n = nt * 16 + (lane_s & 15);
        float v = (k < 100 && n < 100) ? pW2[k * 100 + n] : 0.0f;
        unsigned short hi = bf16_rne(v);
        unsigned short lo = bf16_rne(v - bf16_to_f(hi));
        int addr = (t2 * 64 + lane_s) * 8 + b;
        sHi[addr] = (short)hi;
        sLo[addr] = (short)lo;
    }
    __syncthreads();

    const int lane = threadIdx.x & 63;
    const int widx = threadIdx.x >> 6;
    const long wave_base = ((long)blockIdx.x * 4 + widx) * 256;
    if (wave_base >= (long)B) return;

    const int cg = lane >> 4;     // k-group / row-group 0..3
    const int cl = lane & 15;     // col-in-tile / tile-ownership id

    // hoisted per-lane W3 slice and b2 (col n = nt*16+cl, constant over tiles)
    float w3s[7][3], b2s[7];
#pragma unroll
    for (int nt = 0; nt < 7; ++nt) {
        int n = nt * 16 + cl;
        bool ok = (n < 100);
        b2s[nt] = ok ? pb2[n] : 0.f;
        w3s[nt][0] = ok ? pW3[n * 3 + 0] : 0.f;
        w3s[nt][1] = ok ? pW3[n * 3 + 1] : 0.f;
        w3s[nt][2] = ok ? pW3[n * 3 + 2] : 0.f;
    }
    const float b30 = pb3[0], b31 = pb3[1], b32 = pb3[2];

    float yk[4][3];
#pragma unroll
    for (int r = 0; r < 4; ++r) { yk[r][0] = 0.f; yk[r][1] = 0.f; yk[r][2] = 0.f; }

#pragma unroll 1
    for (int t = 0; t < 16; ++t) {
        const long row = wave_base + t * 16 + cl;
        const float* xp = sa + row * 6;
        float xr[6];
#pragma unroll
        for (int j = 0; j < 6; ++j) xr[j] = xp[j];

        f32x4v c[7];
#pragma unroll
        for (int nt = 0; nt < 7; ++nt) c[nt] = (f32x4v){0.f, 0.f, 0.f, 0.f};

#pragma unroll 1
        for (int kt = 0; kt < 4; ++kt) {
            // A-frag: 8 h1 entries for row (cl), k = kt*32 + cg*8 + b
            short8 ahi, alo;
#pragma unroll
            for (int b = 0; b < 8; ++b) {
                int k = kt * 32 + cg * 8 + b;
                float h = 0.f;
                if (k < 100) {
                    h = pb1[k];
#pragma unroll
                    for (int j = 0; j < 6; ++j)
                        h = fmaf(xr[j], pW1[j * 100 + k], h);
                    h = fmaxf(h, 0.f);
                }
                unsigned short hi = bf16_rne(h);
                unsigned short lo = bf16_rne(h - bf16_to_f(hi));
                ahi[b] = (short)hi;
                alo[b] = (short)lo;
            }
#pragma unroll
            for (int nt = 0; nt < 7; ++nt) {
                int base = ((kt * 7 + nt) * 64 + lane) * 8;
                short8 bhi = *(const short8*)(sHi + base);
                short8 blo = *(const short8*)(sLo + base);
                c[nt] = __builtin_amdgcn_mfma_f32_16x16x32_bf16(ahi, bhi, c[nt], 0, 0, 0);
                c[nt] = __builtin_amdgcn_mfma_f32_16x16x32_bf16(ahi, blo, c[nt], 0, 0, 0);
                c[nt] = __builtin_amdgcn_mfma_f32_16x16x32_bf16(alo, bhi, c[nt], 0, 0, 0);
            }
        }

        // epilogue: +b2, relu, xW3 partials; lane holds rows cg*4+reg, col cl
        float yp[4][3];
#pragma unroll
        for (int r = 0; r < 4; ++r) { yp[r][0] = 0.f; yp[r][1] = 0.f; yp[r][2] = 0.f; }
#pragma unroll
        for (int nt = 0; nt < 7; ++nt) {
            float b2v = b2s[nt];
#pragma unroll
            for (int r = 0; r < 4; ++r) {
                float h2 = fmaxf(c[nt][r] + b2v, 0.f);
                yp[r][0] = fmaf(h2, w3s[nt][0], yp[r][0]);
                yp[r][1] = fmaf(h2, w3s[nt][1], yp[r][1]);
                yp[r][2] = fmaf(h2, w3s[nt][2], yp[r][2]);
            }
        }
        // reduce over cols: lanes differing in bits 0..3 share the same rows
#pragma unroll
        for (int m = 1; m < 16; m <<= 1) {
#pragma unroll
            for (int r = 0; r < 4; ++r) {
                yp[r][0] += __shfl_xor(yp[r][0], m);
                yp[r][1] += __shfl_xor(yp[r][1], m);
                yp[r][2] += __shfl_xor(yp[r][2], m);
            }
        }
        if (cl == t) {
#pragma unroll
            for (int r = 0; r < 4; ++r) {
                yk[r][0] = yp[r][0] + b30;
                yk[r][1] = yp[r][1] + b31;
                yk[r][2] = yp[r][2] + b32;
            }
        }
    }

    // owned rows: wave_base + cl*16 + cg*4 + r, r = 0..3
    const long base2 = wave_base + (long)cl * 16 + cg * 4;
#pragma unroll
    for (int r = 0; r < 4; ++r) {
        float* o = out + (size_t)(base2 + r) * 3;
        o[0] = yk[r][0]; o[1] = yk[r][1]; o[2] = yk[r][2];
    }

    // ---------------- phase 2: ODE RK4 (v9, unchanged) ----------------
    OdeState SP, SQ;
    SP.y0 = (f32x2){yk[0][0], yk[1][0]};
    SP.y1 = (f32x2){yk[0][1], yk[1][1]};
    SP.y2 = (f32x2){yk[0][2], yk[1][2]};
    SQ.y0 = (f32x2){yk[2][0], yk[3][0]};
    SQ.y1 = (f32x2){yk[2][1], yk[3][1]};
    SQ.y2 = (f32x2){yk[2][2], yk[3][2]};
    const float c0 = ob2[0], c1 = ob2[1], c2 = ob2[2];

    relin_begin(SP, c0, c1, c2);
    relin_begin(SQ, c0, c1, c2);

#pragma unroll 1
    for (int s = 0; s < 15; ++s) {
        float dt  = T[s + 1] - T[s];
        float hdt = 0.5f * dt;

        if ((s % 3) == 0) {
            relin_begin(SP, c0, c1, c2);
            relin_begin(SQ, c0, c1, c2);
#pragma unroll 1
            for (int j0 = 0; j0 < 100; j0 += 4) {
                float4 z  = *(const float4*)(ob1 + j0);
                float4 wa = *(const float4*)(oW1 + 0   + j0);
                float4 wb = *(const float4*)(oW1 + 100 + j0);
                float4 wc = *(const float4*)(oW1 + 200 + j0);
                float4 u0 = *(const float4*)(oW2 + j0 * 3 + 0);
                float4 u1 = *(const float4*)(oW2 + j0 * 3 + 4);
                float4 u2 = *(const float4*)(oW2 + j0 * 3 + 8);
                accum_quad(SP, z, wa, wb, wc, u0, u1, u2);
                accum_quad(SQ, z, wa, wb, wc, u0, u1, u2);
            }
        }

        rk4_step(SP, dt, hdt);
        rk4_step(SQ, dt, hdt);

        float* base = out + (size_t)(s + 1) * (size_t)B * 3;
        float* o0 = base + (size_t)(base2 + 0) * 3;
        o0[0] = SP.y0.x; o0[1] = SP.y1.x; o0[2] = SP.y2.x;
        float* o1 = base + (size_t)(base2 + 1) * 3;
        o1[0] = SP.y0.y; o1[1] = SP.y1.y; o1[2] = SP.y2.y;
        float* o2 = base + (size_t)(base2 + 2) * 3;
        o2[0] = SQ.y0.x; o2[1] = SQ.y1.x; o2[2] = SQ.y2.x;
        float* o3 = base + (size_t)(base2 + 3) * 3;
        o3[0] = SQ.y0.y; o3[1] = SQ.y1.y; o3[2] = SQ.y2.y;
    }
}

extern "C" void kernel_launch(void* const* d_in, const int* in_sizes, int n_in,
                              void* d_out, int out_size, void* d_ws, size_t ws_size,
                              hipStream_t stream) {
    const float* sa  = (const float*)d_in[0];
    const float* T   = (const float*)d_in[1];
    const float* pW1 = (const float*)d_in[2];
    const float* pb1 = (const float*)d_in[3];
    const float* pW2 = (const float*)d_in[4];
    const float* pb2 = (const float*)d_in[5];
    const float* pW3 = (const float*)d_in[6];
    const float* pb3 = (const float*)d_in[7];
    const float* oW1 = (const float*)d_in[8];
    const float* ob1 = (const float*)d_in[9];
    const float* oW2 = (const float*)d_in[10];
    const float* ob2 = (const float*)d_in[11];
    float* out = (float*)d_out;

    const int B = in_sizes[0] / 6;            // 524288
    const int grid = B / 1024;                // 512 blocks x 4 waves x 256 rows

    fused_kernel<<<grid, 256, 0, stream>>>(sa, pW1, pb1, pW2, pb2, pW3, pb3,
                                           T, oW1, ob1, oW2, ob2, out, B);
}